// Round 8
// baseline (364.564 us; speedup 1.0000x reference)
//
#include <hip/hip_runtime.h>
#include <hip/hip_bf16.h>
#include <math.h>

#define BB 8
#define TT 1024
#define DD 512
#define FFD 2048
#define HH 8
#define HDD 64
#define KW 15
#define MR (BB*TT)   // 8192 rows
#define QKVN 1536

typedef __attribute__((ext_vector_type(8))) short short8;   // 8 bf16 = 4 VGPRs
typedef __attribute__((ext_vector_type(4))) short short4v;  // 8 bytes
typedef __attribute__((ext_vector_type(4))) float f32x4;
typedef __hip_bfloat16 bf16;

__device__ __forceinline__ float bf2f(unsigned u16) {
    return __uint_as_float(u16 << 16);
}

__device__ __forceinline__ void async_copy16(const void* g, void* l) {
    __builtin_amdgcn_global_load_lds(
        (const __attribute__((address_space(1))) void*)g,
        (__attribute__((address_space(3))) void*)l, 16, 0, 0);
}

__device__ __forceinline__ float gelu_exact(float v) {
    return 0.5f * v * (1.0f + erff(v * 0.70710678118654752f));
}

// ---------------------------------------------------------------------------
// Prep super-kernel: blocks 0..1535 weight transpose, 1536 bias concat,
// 1537..3584 dual LayerNorm (LN1+LNa share row stats). All independent.
// ---------------------------------------------------------------------------
struct PrepPack {
    const float* src[10];
    bf16*        dst[10];
    int          K[10];
    int          lgNT[10];
    float        scale[10];
    int          off[10];
    const float* bq; const float* bk; const float* bv;
    float*       bdst;
    const float* x;
    const float* g1; const float* b1; const float* ga; const float* ba;
    bf16* o1; bf16* o2;
};

__global__ __launch_bounds__(256) void prep_kernel(PrepPack P) {
    __shared__ alignas(16) bf16 T[64][72];
    const int bid = blockIdx.x;
    if (bid == 1536) {   // bias concat
        #pragma unroll
        for (int it = 0; it < 6; ++it) {
            int i = it * 256 + threadIdx.x;
            float v = i < 512 ? P.bq[i] * 0.125f
                              : (i < 1024 ? P.bk[i - 512] : P.bv[i - 1024]);
            P.bdst[i] = v;
        }
        return;
    }
    if (bid > 1536) {    // dual LN: 4 rows per block (wave per row)
        int wave = ((bid - 1537) * 256 + (int)threadIdx.x) >> 6;
        int lane = threadIdx.x & 63;
        const float* row = P.x + (size_t)wave * DD;
        float4 v0 = ((const float4*)row)[lane];
        float4 v1 = ((const float4*)row)[64 + lane];
        float s  = v0.x + v0.y + v0.z + v0.w + v1.x + v1.y + v1.z + v1.w;
        float ss = v0.x*v0.x + v0.y*v0.y + v0.z*v0.z + v0.w*v0.w
                 + v1.x*v1.x + v1.y*v1.y + v1.z*v1.z + v1.w*v1.w;
        #pragma unroll
        for (int off = 32; off >= 1; off >>= 1) {
            s  += __shfl_xor(s,  off, 64);
            ss += __shfl_xor(ss, off, 64);
        }
        float mean = s * (1.0f / DD);
        float var  = ss * (1.0f / DD) - mean * mean;
        float r    = rsqrtf(var + 1e-3f);
        float n0x = (v0.x - mean) * r, n0y = (v0.y - mean) * r,
              n0z = (v0.z - mean) * r, n0w = (v0.w - mean) * r;
        float n1x = (v1.x - mean) * r, n1y = (v1.y - mean) * r,
              n1z = (v1.z - mean) * r, n1w = (v1.w - mean) * r;
        {
            float4 g0 = ((const float4*)P.g1)[lane];
            float4 gg = ((const float4*)P.g1)[64 + lane];
            float4 b0 = ((const float4*)P.b1)[lane];
            float4 bb = ((const float4*)P.b1)[64 + lane];
            alignas(8) bf16 o0[4], o1[4];
            o0[0] = __float2bfloat16(n0x * g0.x + b0.x);
            o0[1] = __float2bfloat16(n0y * g0.y + b0.y);
            o0[2] = __float2bfloat16(n0z * g0.z + b0.z);
            o0[3] = __float2bfloat16(n0w * g0.w + b0.w);
            o1[0] = __float2bfloat16(n1x * gg.x + bb.x);
            o1[1] = __float2bfloat16(n1y * gg.y + bb.y);
            o1[2] = __float2bfloat16(n1z * gg.z + bb.z);
            o1[3] = __float2bfloat16(n1w * gg.w + bb.w);
            bf16* orow = P.o1 + (size_t)wave * DD;
            *(short4v*)(orow + lane * 4)       = *(const short4v*)o0;
            *(short4v*)(orow + 256 + lane * 4) = *(const short4v*)o1;
        }
        {
            float4 g0 = ((const float4*)P.ga)[lane];
            float4 gg = ((const float4*)P.ga)[64 + lane];
            float4 b0 = ((const float4*)P.ba)[lane];
            float4 bb = ((const float4*)P.ba)[64 + lane];
            alignas(8) bf16 o0[4], o1[4];
            o0[0] = __float2bfloat16(n0x * g0.x + b0.x);
            o0[1] = __float2bfloat16(n0y * g0.y + b0.y);
            o0[2] = __float2bfloat16(n0z * g0.z + b0.z);
            o0[3] = __float2bfloat16(n0w * g0.w + b0.w);
            o1[0] = __float2bfloat16(n1x * gg.x + bb.x);
            o1[1] = __float2bfloat16(n1y * gg.y + bb.y);
            o1[2] = __float2bfloat16(n1z * gg.z + bb.z);
            o1[3] = __float2bfloat16(n1w * gg.w + bb.w);
            bf16* orow = P.o2 + (size_t)wave * DD;
            *(short4v*)(orow + lane * 4)       = *(const short4v*)o0;
            *(short4v*)(orow + 256 + lane * 4) = *(const short4v*)o1;
        }
        return;
    }
    // weight transpose tile
    int e = 0;
    #pragma unroll
    for (int i = 1; i < 10; ++i) e = (bid >= P.off[i]) ? i : e;
    const float* W  = P.src[e];
    bf16*        Wt = P.dst[e];
    const int    K  = P.K[e];
    const int    lg = P.lgNT[e];
    const float  scale = P.scale[e];
    const int local = bid - P.off[e];
    const int bx = local & ((1 << lg) - 1);
    const int by = local >> lg;
    const int k0 = by * 64;
    const int n0 = bx * 64;
    const int N  = (1 << lg) * 64;
    const int tid = threadIdx.x;
    #pragma unroll
    for (int it = 0; it < 4; ++it) {
        int lin = it * 256 + tid;
        int kl  = lin >> 4;
        int nq  = (lin & 15) * 4;
        float4 v = *(const float4*)(W + (size_t)(k0 + kl) * N + n0 + nq);
        T[nq + 0][kl] = __float2bfloat16(v.x * scale);
        T[nq + 1][kl] = __float2bfloat16(v.y * scale);
        T[nq + 2][kl] = __float2bfloat16(v.z * scale);
        T[nq + 3][kl] = __float2bfloat16(v.w * scale);
    }
    __syncthreads();
    #pragma unroll
    for (int it = 0; it < 4; ++it) {
        int lin = it * 256 + tid;
        int nl  = lin >> 4;
        int kq  = (lin & 15) * 4;
        *(short4v*)(Wt + (size_t)(n0 + nl) * K + k0 + kq) = *(const short4v*)&T[nl][kq];
    }
}

// ---------------------------------------------------------------------------
// Generic bf16 MFMA GEMM — 2-phase double-buffered pipeline (counted vmcnt).
// OUTMODE: 0 fp32, 1 bf16*oscale. RESMODE: 0/1 (+fp32 res1)
// /2 (+res1 + s2*bf16 res2).
// ---------------------------------------------------------------------------
template<int BN, int OP, int RESMODE, int OUTMODE>
__global__ __launch_bounds__(256) void bgemm_kernel(
    const bf16* __restrict__ A,
    const bf16* __restrict__ Bt,
    const float* __restrict__ bias,
    const float* __restrict__ res1,
    const bf16* __restrict__ res2,
    float s2, float oscale,
    void* __restrict__ Cout,
    int N, int Kd, int nxb)
{
    constexpr int NT = BN / 32;
    constexpr int S  = 4 + BN / 32;    // async issues per stage per thread
    __shared__ alignas(16) bf16 As[2][128][64];
    __shared__ alignas(16) bf16 Bs[2][BN][64];
    const int tid  = threadIdx.x;
    const int w    = tid >> 6;
    const int lane = tid & 63;
    const int quad = lane >> 4;
    const int l16  = lane & 15;
    const int wm   = w >> 1, wn = w & 1;

    const int flat = blockIdx.x;
    const int c8   = flat & 7;
    const int j    = flat >> 3;
    const int jy   = j / nxb;
    const int m0   = (c8 * 8 + jy) * 128;
    const int n0   = (j - jy * nxb) * BN;

    const int srow = lane >> 3;
    const int scol = ((lane & 7) ^ srow) * 8;

    const bf16* Ap = A  + (size_t)(m0 + w * 32 + srow) * Kd + scol;
    const bf16* Bp = Bt + (size_t)(n0 + w * (BN / 4) + srow) * Kd + scol;

    f32x4 acc[4][NT] = {};
    const int nk = Kd >> 6;

#define BSTAGE(bb, kk) do { \
        _Pragma("unroll") \
        for (int i = 0; i < 4; ++i) \
            async_copy16(Ap + (size_t)(i * 8) * Kd + (kk), &As[bb][w * 32 + i * 8][0]); \
        _Pragma("unroll") \
        for (int i = 0; i < BN / 32; ++i) \
            async_copy16(Bp + (size_t)(i * 8) * Kd + (kk), &Bs[bb][w * (BN / 4) + i * 8][0]); \
    } while (0)

    BSTAGE(0, 0);
    for (int t = 0; t < nk; ++t) {
        const int cur = t & 1;
        if (t + 1 < nk) {
            BSTAGE(cur ^ 1, (t + 1) * 64);
            if constexpr (S == 6) asm volatile("s_waitcnt vmcnt(6)" ::: "memory");
            else                  asm volatile("s_waitcnt vmcnt(8)" ::: "memory");
        } else {
            asm volatile("s_waitcnt vmcnt(0)" ::: "memory");
        }
        __builtin_amdgcn_s_barrier();
        __builtin_amdgcn_sched_barrier(0);
        __builtin_amdgcn_s_setprio(1);
        #pragma unroll
        for (int ks = 0; ks < 2; ++ks) {
            short8 af[4], bfr[NT];
            #pragma unroll
            for (int mt = 0; mt < 4; ++mt) {
                const int row = wm * 64 + mt * 16 + l16;
                const int c   = ((ks * 4 + quad) ^ (row & 7)) * 16;
                af[mt] = *(const short8*)((const char*)&As[cur][row][0] + c);
            }
            #pragma unroll
            for (int nt = 0; nt < NT; ++nt) {
                const int col = wn * (BN / 2) + nt * 16 + l16;
                const int c   = ((ks * 4 + quad) ^ (col & 7)) * 16;
                bfr[nt] = *(const short8*)((const char*)&Bs[cur][col][0] + c);
            }
            #pragma unroll
            for (int mt = 0; mt < 4; ++mt)
                #pragma unroll
                for (int nt = 0; nt < NT; ++nt)
                    acc[mt][nt] = __builtin_amdgcn_mfma_f32_16x16x32_bf16(
                        af[mt], bfr[nt], acc[mt][nt], 0, 0, 0);
        }
        __builtin_amdgcn_s_setprio(0);
        asm volatile("" ::: "memory");
        __builtin_amdgcn_s_barrier();
    }
#undef BSTAGE

    const int crow0 = m0 + wm * 64 + quad * 4;
    const int ccol0 = n0 + wn * (BN / 2) + l16;
    #pragma unroll
    for (int nt = 0; nt < NT; ++nt) {
        const int col = ccol0 + nt * 16;
        const float bv = bias[col];
        #pragma unroll
        for (int mt = 0; mt < 4; ++mt) {
            #pragma unroll
            for (int r = 0; r < 4; ++r) {
                const int row = crow0 + mt * 16 + r;
                const size_t off = (size_t)row * N + col;
                float o = acc[mt][nt][r] + bv;
                if (OP == 1)      o = fmaxf(o, 0.f);
                else if (OP == 2) o = gelu_exact(o);
                if (RESMODE >= 1) o += res1[off];
                if (RESMODE == 2) o += s2 * __bfloat162float(res2[off]);
                if (OUTMODE == 0) ((float*)Cout)[off] = o;
                else              ((bf16*)Cout)[off]  = __float2bfloat16(o * oscale);
            }
        }
    }
}

// ---------------------------------------------------------------------------
// Fused full-row GEMM + residuals + LayerNorm (replaces steps 4+5 and 8+9).
// Tile BM=32 x BN=512 (full row width) so each block owns complete rows.
// ---------------------------------------------------------------------------
template<int NK, int RESMODE>
__global__ __launch_bounds__(512, 1) void fusedln_kernel(
    const bf16* __restrict__ A, const bf16* __restrict__ Bt,
    const float* __restrict__ bias,
    const float* __restrict__ res1, const bf16* __restrict__ res2, float s2,
    float* __restrict__ outF,
    const float* __restrict__ g, const float* __restrict__ bb,
    bf16* __restrict__ lnout)
{
    constexpr int Kd = NK * 64;
    __shared__ alignas(16) char lds[2 * 69632];   // buf: B[512][128B] + A[32][128B]
    const int tid  = threadIdx.x;
    const int w    = tid >> 6;
    const int lane = tid & 63;
    const int quad = lane >> 4;
    const int l16  = lane & 15;
    const int wm   = w >> 2, wn = w & 3;
    const int m0   = (int)blockIdx.x * 32;

    const int srow = lane >> 3;
    const int swz  = ((lane & 7) ^ srow) * 8;   // pre-swizzled source chunk
    const bf16* BpS = Bt + (size_t)(w * 64 + srow) * Kd + swz;
    const bf16* ApS = A  + (size_t)(m0 + (w & 3) * 8 + srow) * Kd + swz;

#define FSTG(kc, base) do { \
        _Pragma("unroll") \
        for (int i = 0; i < 8; ++i) \
            async_copy16(BpS + (size_t)(i * 8) * Kd + (kc), \
                         lds + (base) + (w * 64 + i * 8) * 128); \
        if (w < 4) \
            async_copy16(ApS + (kc), \
                         lds + (base) + 65536 + ((w & 3) * 8) * 128); \
    } while (0)

    const int cxa0 = ((quad)     ^ (l16 & 7)) * 16;
    const int cxa1 = ((4 + quad) ^ (l16 & 7)) * 16;

    f32x4 acc[8] = {};

    FSTG(0, 0);
    asm volatile("s_waitcnt vmcnt(0)" ::: "memory");

    for (int t = 0; t < NK; ++t) {
        const int cb = (t & 1) * 69632;
        asm volatile("" ::: "memory");
        __builtin_amdgcn_s_barrier();
        __builtin_amdgcn_sched_barrier(0);
        if (t + 1 < NK) FSTG((t + 1) * 64, ((t + 1) & 1) * 69632);

        const char* abase = lds + cb + 65536 + (wm * 16 + l16) * 128;
        short8 a0 = *(const short8*)(abase + cxa0);
        short8 a1 = *(const short8*)(abase + cxa1);
        #pragma unroll
        for (int nt = 0; nt < 8; ++nt) {
            const char* bbase = lds + cb + (wn * 128 + nt * 16 + l16) * 128;
            short8 b0 = *(const short8*)(bbase + cxa0);
            short8 b1 = *(const short8*)(bbase + cxa1);
            acc[nt] = __builtin_amdgcn_mfma_f32_16x16x32_bf16(a0, b0, acc[nt], 0, 0, 0);
            acc[nt] = __builtin_amdgcn_mfma_f32_16x16x32_bf16(a1, b1, acc[nt], 0, 0, 0);
        }
        asm volatile("s_waitcnt vmcnt(0)" ::: "memory");
    }
#undef FSTG

    // ---- epilogue: residuals + fp32 store + in-register LN ----
    const int row0 = m0 + wm * 16 + quad * 4;
    float val[8][4];
    float s[4] = {0.f, 0.f, 0.f, 0.f}, ss[4] = {0.f, 0.f, 0.f, 0.f};
    #pragma unroll
    for (int nt = 0; nt < 8; ++nt) {
        const int col = wn * 128 + nt * 16 + l16;
        const float bv = bias[col];
        #pragma unroll
        for (int r = 0; r < 4; ++r) {
            const size_t off = (size_t)(row0 + r) * DD + col;
            float o = acc[nt][r] + bv;
            if (RESMODE >= 1) o += res1[off];
            if (RESMODE == 2) o += s2 * __bfloat162float(res2[off]);
            outF[off] = o;
            val[nt][r] = o;
            s[r]  += o;
            ss[r] += o * o;
        }
    }
    #pragma unroll
    for (int off = 8; off >= 1; off >>= 1) {
        #pragma unroll
        for (int r = 0; r < 4; ++r) {
            s[r]  += __shfl_xor(s[r],  off, 64);
            ss[r] += __shfl_xor(ss[r], off, 64);
        }
    }
    __syncthreads();
    float2* red = (float2*)lds;    // [wn 4][row 32]
    if (l16 == 0) {
        #pragma unroll
        for (int r = 0; r < 4; ++r) {
            float2 v; v.x = s[r]; v.y = ss[r];
            red[wn * 32 + (wm * 16 + quad * 4 + r)] = v;
        }
    }
    __syncthreads();
    float mean[4], rstd[4];
    #pragma unroll
    for (int r = 0; r < 4; ++r) {
        float a = 0.f, b2 = 0.f;
        #pragma unroll
        for (int q = 0; q < 4; ++q) {
            float2 v = red[q * 32 + (wm * 16 + quad * 4 + r)];
            a += v.x; b2 += v.y;
        }
        const float m = a * (1.0f / DD);
        const float var = b2 * (1.0f / DD) - m * m;
        mean[r] = m;
        rstd[r] = rsqrtf(var + 1e-3f);
    }
    #pragma unroll
    for (int nt = 0; nt < 8; ++nt) {
        const int col = wn * 128 + nt * 16 + l16;
        const float gv = g[col], bv2 = bb[col];
        #pragma unroll
        for (int r = 0; r < 4; ++r) {
            const size_t off = (size_t)(row0 + r) * DD + col;
            lnout[off] = __float2bfloat16(
                (val[nt][r] - mean[r]) * rstd[r] * gv + bv2);
        }
    }
}

// ---------------------------------------------------------------------------
// 256x256-tile GEMM (K=512), 512 threads = 8 waves, v6: BK=32 with a 4-deep
// ring of 32 KB buffers (128 KB total). stage(t+3) issued at tile-t bottom;
// counted s_waitcnt vmcnt(8) at tile-top keeps stages t+1,t+2 permanently in
// flight (T4: never drain) -> every load gets ~2.7 tiles (~3000 cyc) of
// latency slack vs v5's <1 tile + vmcnt(0) drain. One barrier per tile;
// compute block (12 ds_read_b128 + 32 MFMA) compiler-scheduled.
// LDS rows stored as paired-128B (2 BK=32 rows per 128B) with XOR chunk
// swizzle; staging source pre-swizzled (both-sides rule); read pattern =
// 8 groups x 8 lanes = conflict-free minimum.
//   blocks 0..nffblk-1 : out = relu(Aff @ Btff^T + biasff) -> bf16 [8192,2048]
//   blocks >= nffblk   : qkv job (Q/K -> qkvb, V -> Vtb transposed)
// ---------------------------------------------------------------------------
__global__ __launch_bounds__(512, 2) void gemm256_kernel(
    const bf16* __restrict__ Aff, const bf16* __restrict__ Btff,
    const float* __restrict__ biasff, bf16* __restrict__ outff,
    const bf16* __restrict__ Aqk, const bf16* __restrict__ Btqk,
    const float* __restrict__ biasqk, bf16* __restrict__ qkvb,
    bf16* __restrict__ Vtb, int nffblk)
{
    __shared__ alignas(16) char lds[131072];   // 4 ring buffers x 32 KB
    const int tid  = threadIdx.x;
    const int w    = tid >> 6;
    const int lane = tid & 63;
    const int quad = lane >> 4;
    const int l16  = lane & 15;
    const int ms   = w >> 2, ns = w & 3;

    const bool jobq = (int)blockIdx.x >= nffblk;
    const int  flat = jobq ? (int)blockIdx.x - nffblk : (int)blockIdx.x;
    const int  nxb  = jobq ? 6 : 8;
    const bf16* A   = jobq ? Aqk : Aff;
    const bf16* Bt  = jobq ? Btqk : Btff;
    const float* bias = jobq ? biasqk : biasff;

    const int c8 = flat & 7;
    const int j  = flat >> 3;
    const int jy = j / nxb;
    const int m0 = (c8 * 4 + jy) * 256;
    const int n0 = (j - jy * nxb) * 256;

    // ---- staging (per tile: A 16 KB + B 16 KB; 2+2 loads/thread) ----
    // 1 KB slab = 16 rows x 64B (BK=32). lane l -> localRow, srcChunk with
    // pre-swizzle: stored chunk (l&3) holds source chunk (l&3)^((l>>3)&3).
    const int lrow = ((lane >> 3) << 1) | ((lane >> 2) & 1);
    const int scnk = ((lane & 3) ^ ((lane >> 3) & 3)) * 8;
    const bf16* ApS = A  + (size_t)(m0 + w * 32 + lrow) * DD + scnk;
    const bf16* BpS = Bt + (size_t)(n0 + w * 32 + lrow) * DD + scnk;

#define STG(tt) do { \
        const int kc_ = (tt) * 32; \
        char* bb_ = lds + ((tt) & 3) * 32768; \
        async_copy16(ApS + kc_,           bb_ + (w * 2) * 1024); \
        async_copy16(ApS + 16 * DD + kc_, bb_ + (w * 2 + 1) * 1024); \
        async_copy16(BpS + kc_,           bb_ + 16384 + (w * 2) * 1024); \
        async_copy16(BpS + 16 * DD + kc_, bb_ + 16384 + (w * 2 + 1) * 1024); \
    } while (0)

    // ---- fragment read offsets: row r -> (r>>1)*128 + (r&1)*64 +
    //      ((quad^((r>>1)&3)))*16; per-thread constant part: ----
    const int l8 = l16 >> 1;
    const int fo = l8 * 128 + (l16 & 1) * 64 + ((quad ^ (l8 & 3))) * 16;
    const int aoff = ms * 4096 + fo;           // + QM*8192 + mt*1024
    const int boff = 16384 + ns * 2048 + fo;   // + QN*8192 + nt*1024

    f32x4 acc[8][4] = {};

    // prologue: 3 tiles in flight (12 loads/thread)
    STG(0); STG(1); STG(2);

    for (int t = 0; t < 16; ++t) {
        // counted wait: ensure THIS wave's stage(t) landed, keep t+1,t+2 flying
        if (t < 14)      asm volatile("s_waitcnt vmcnt(8)" ::: "memory");
        else if (t == 14) asm volatile("s_waitcnt vmcnt(4)" ::: "memory");
        else             asm volatile("s_waitcnt vmcnt(0)" ::: "memory");
        __builtin_amdgcn_s_barrier();
        __builtin_amdgcn_sched_barrier(0);

        const char* buf = lds + (t & 3) * 32768;
        short8 bfrag[2][2];
        #pragma unroll
        for (int QN = 0; QN < 2; ++QN)
            #pragma unroll
            for (int nt = 0; nt < 2; ++nt)
                bfrag[QN][nt] = *(const short8*)(buf + boff + QN * 8192 + nt * 1024);
        #pragma unroll
        for (int QM = 0; QM < 2; ++QM) {
            short8 afr[4];
            #pragma unroll
            for (int mt = 0; mt < 4; ++mt)
                afr[mt] = *(const short8*)(buf + aoff + QM * 8192 + mt * 1024);
            #pragma unroll
            for (int QN = 0; QN < 2; ++QN)
                #pragma unroll
                for (int mt = 0; mt < 4; ++mt)
                    #pragma unroll
                    for (int nt = 0; nt < 2; ++nt)
                        acc[QM * 4 + mt][QN * 2 + nt] =
                            __builtin_amdgcn_mfma_f32_16x16x32_bf16(
                                afr[mt], bfrag[QN][nt],
                                acc[QM * 4 + mt][QN * 2 + nt], 0, 0, 0);
        }

        // stage 3 tiles ahead into the slot whose reads finished pre-barrier
        if (t + 3 < 16) STG(t + 3);
    }
#undef STG

    // epilogue: frag (QM,mt) x (QN,nt); row = m0+QM*128+ms*64+mt*16+quad*4+r,
    // col = n0+QN*128+ns*32+nt*16+l16   (identical to v5)
    #pragma unroll
    for (int QN = 0; QN < 2; ++QN) {
        #pragma unroll
        for (int nt = 0; nt < 2; ++nt) {
            const int col = n0 + QN * 128 + ns * 32 + nt * 16 + l16;
            const float bv = bias[col];
            #pragma unroll
            for (int QM = 0; QM < 2; ++QM) {
                #pragma unroll
                for (int mt = 0; mt < 4; ++mt) {
                    const f32x4 av = acc[QM * 4 + mt][QN * 2 + nt];
                    const int rowt = m0 + QM * 128 + ms * 64 + mt * 16 + quad * 4;
                    if (jobq) {
                        alignas(8) bf16 o4[4];
                        #pragma unroll
                        for (int r = 0; r < 4; ++r)
                            o4[r] = __float2bfloat16(av[r] + bv);
                        if (col < 1024) {
                            #pragma unroll
                            for (int r = 0; r < 4; ++r)
                                qkvb[(size_t)(rowt + r) * QKVN + col] = o4[r];
                        } else {
                            const int dg  = col - 1024;
                            const int bbk = rowt >> 10, t0 = rowt & 1023;
                            const int bh2 = bbk * 8 + (dg >> 6), d = dg & 63;
                            *(short4v*)(Vtb + ((size_t)bh2 * 64 + d) * TT + t0) =
                                *(const short4v*)o4;
                        }
                    } else {
                        #pragma unroll
                        for (int r = 0; r < 4; ++r) {
                            const float o = fmaxf(av[r] + bv, 0.f);
                            outff[(size_t)(rowt + r) * FFD + col] =
                                __float2bfloat16(o);
                        }
                    }
                }
            }
        }
    }
}

// ---------------------------------------------------------------------------
// Fused FF2 + flash-attention super-kernel. Parity-interleaved: even blocks
// = attention (512), odd blocks = FF2 (512). FF2 is 2-phase double-buffered
// (counted vmcnt(6)). 48 KB LDS union -> 3 blocks/CU. Attention MFMA
// clusters wrapped in setprio(1) (T5).
// ---------------------------------------------------------------------------
__global__ __launch_bounds__(256) void ff2attn_kernel(
    const bf16* __restrict__ QKV, const bf16* __restrict__ Vt,
    bf16* __restrict__ ctx,
    const bf16* __restrict__ bigb, const bf16* __restrict__ Wff2t,
    const float* __restrict__ bff2, bf16* __restrict__ xffb)
{
    __shared__ alignas(16) bf16 smem[24576];   // 48 KB
    const int tid  = threadIdx.x;
    const int w    = tid >> 6;
    const int lane = tid & 63;
    const int quad = lane >> 4;
    const int l16  = lane & 15;
    const int half = (int)blockIdx.x >> 1;

    if ((blockIdx.x & 1) == 0) {
        // ---------------- flash attention v4 ----------------
        typedef bf16 (*tile_t)[64][64];
        tile_t Ks = (tile_t)smem;                    // Ks[2][64][64]
        tile_t Vs = (tile_t)(smem + 2 * 64 * 64);    // Vs[2][64][64]
        const int bh = half & 63;
        const int bi = 7 - (half >> 6);              // long blocks first
        const int b = bh >> 3, h = bh & 7;

        const bf16* Qg = QKV + (size_t)(b * TT) * QKVN + h * 64;
        const bf16* Kg = QKV + (size_t)(b * TT) * QKVN + 512 + h * 64;
        const bf16* Vg = Vt  + (size_t)bh * 64 * TT;

        const int qL = bi * 128 + w * 16;
        const int qH = qL + 64;
        short8 qfL0 = *(const short8*)(Qg + (size_t)(qL + l16) * QKVN + quad * 8);
        short8 qfL1 = *(const short8*)(Qg + (size_t)(qL + l16) * QKVN + 32 + quad * 8);
        short8 qfH0 = *(const short8*)(Qg + (size_t)(qH + l16) * QKVN + quad * 8);
        short8 qfH1 = *(const short8*)(Qg + (size_t)(qH + l16) * QKVN + 32 + quad * 8);

        const int sgrow  = lane >> 3;
        const int sgchnk = lane & 7;

        f32x4 caccL[4] = {}, caccH[4] = {};
        float lL = 0.f, lH = 0.f;
        const int prow_base = ((l16 >> 2) << 3) + (l16 & 3);
        const int smax = 2 * bi + 1;

        #pragma unroll
        for (int i = 0; i < 2; ++i) {
            const int rowbase = w * 8 + i * 32;
            const int row = rowbase + sgrow;
            const int fR = (row & 3) | (((row >> 3) & 1) << 2);
            const int sc = sgchnk ^ fR;
            async_copy16(Kg + (size_t)row * QKVN + sc * 8, &Ks[0][rowbase][0]);
            async_copy16(Vg + (size_t)row * TT + sc * 8,   &Vs[0][rowbase][0]);
        }

        int buf = 0;
        for (int s = 0; s <= smax; ++s) {
            __syncthreads();
            if (s < smax) {
                const int kn = (s + 1) * 64;
                #pragma unroll
                for (int i = 0; i < 2; ++i) {
                    const int rowbase = w * 8 + i * 32;
                    const int row = rowbase + sgrow;
                    const int fR = (row & 3) | (((row >> 3) & 1) << 2);
                    const int sc = sgchnk ^ fR;
                    async_copy16(Kg + (size_t)(kn + row) * QKVN + sc * 8,
                                 &Ks[buf ^ 1][rowbase][0]);
                    async_copy16(Vg + (size_t)row * TT + kn + sc * 8,
                                 &Vs[buf ^ 1][rowbase][0]);
                }
            }
            const int k0 = s * 64;
            const bool doL = (s < smax);

            f32x4 sTL[4], sTH[4];
            __builtin_amdgcn_s_setprio(1);
            #pragma unroll
            for (int s4 = 0; s4 < 4; ++s4) {
                const int prow = prow_base + (s4 >> 1) * 32 + (s4 & 1) * 4;
                const int fR = (prow & 3) | (((prow >> 3) & 1) << 2);
                short8 ka = *(const short8*)&Ks[buf][prow][(quad ^ fR) * 8];
                short8 kb = *(const short8*)&Ks[buf][prow][((4 + quad) ^ fR) * 8];
                f32x4 zH = {0.f, 0.f, 0.f, 0.f};
                zH = __builtin_amdgcn_mfma_f32_16x16x32_bf16(ka, qfH0, zH, 0, 0, 0);
                sTH[s4] = __builtin_amdgcn_mfma_f32_16x16x32_bf16(kb, qfH1, zH, 0, 0, 0);
                if (doL) {
                    f32x4 zL = {0.f, 0.f, 0.f, 0.f};
                    zL = __builtin_amdgcn_mfma_f32_16x16x32_bf16(ka, qfL0, zL, 0, 0, 0);
                    sTL[s4] = __builtin_amdgcn_mfma_f32_16x16x32_bf16(kb, qfL1, zL, 0, 0, 0);
                }
            }
            __builtin_amdgcn_s_setprio(0);

            alignas(16) bf16 pbH[16], pbL[16];
            if (s == smax) {
                const int qg = qH + l16;
                #pragma unroll
                for (int s4 = 0; s4 < 4; ++s4)
                    #pragma unroll
                    for (int r = 0; r < 4; ++r) {
                        const int key = k0 + (s4 >> 1) * 32 + quad * 8 + (s4 & 1) * 4 + r;
                        const float p = (key <= qg) ? __expf(sTH[s4][r]) : 0.f;
                        lH += p;
                        pbH[s4 * 4 + r] = __float2bfloat16(p);
                    }
            } else {
                #pragma unroll
                for (int s4 = 0; s4 < 4; ++s4)
                    #pragma unroll
                    for (int r = 0; r < 4; ++r) {
                        const float p = __expf(sTH[s4][r]);
                        lH += p;
                        pbH[s4 * 4 + r] = __float2bfloat16(p);
                    }
            }
            if (doL) {
                if (s == smax - 1) {
                    const int qg = qL + l16;
                    #pragma unroll
                    for (int s4 = 0; s4 < 4; ++s4)
                        #pragma unroll
                        for (int r = 0; r < 4; ++r) {
                            const int key = k0 + (s4 >> 1) * 32 + quad * 8 + (s4 & 1) * 4 + r;
                            const float p = (key <= qg) ? __expf(sTL[s4][r]) : 0.f;
                            lL += p;
                            pbL[s4 * 4 + r] = __float2bfloat16(p);
                        }
                } else {
                    #pragma unroll
                    for (int s4 = 0; s4 < 4; ++s4)
                        #pragma unroll
                        for (int r = 0; r < 4; ++r) {
                            const float p = __expf(sTL[s4][r]);
                            lL += p;
                            pbL[s4 * 4 + r] = __float2bfloat16(p);
                        }
                }
            }
            const short8 pfH0 = *(const short8*)&pbH[0];
            const short8 pfH1 = *(const short8*)&pbH[8];
            const short8 pfL0 = *(const short8*)&pbL[0];
            const short8 pfL1 = *(const short8*)&pbL[8];

            __builtin_amdgcn_s_setprio(1);
            #pragma unroll
            for (int gg = 0; gg < 4; ++gg) {
                const int vrow = gg * 16 + l16;
                const int fR = (vrow & 3) | (((vrow >> 3) & 1) << 2);
                short8 va = *(const short8*)&Vs[buf][vrow][(quad ^ fR) * 8];
                short8 vb = *(const short8*)&Vs[buf][vrow][((4 + quad) ^ fR) * 8];
                caccH[gg] = __builtin_amdgcn_mfma_f32_16x16x32_bf16(va, pfH0, caccH[gg], 0, 0, 0);
                caccH[gg] = __builtin_amdgcn_mfma_f32_16x16x32_bf16(vb, pfH1, caccH[gg], 0, 0, 0);
                if (doL) {
                    caccL[gg] = __builtin_amdgcn_mfma_f32_16x16x32_bf16(va, pfL0, caccL[gg], 0, 0, 0);
                    caccL[gg] = __builtin_amdgcn_mfma_f32_16x16x32_bf16(vb, pfL1, caccL[gg], 0, 0, 0);
                }
            }
            __builtin_amdgcn_s_setprio(0);
            buf ^= 1;
        }

        lL += __shfl_xor(lL, 16, 64);
        lL += __shfl_xor(lL, 32, 64);
        lH += __shfl_xor(lH, 16, 64);
        lH += __shfl_xor(lH, 32, 64);
        const float invL = 1.0f / lL;
        const float invH = 1.0f / lH;

        bf16* CbL = ctx + (size_t)(b * TT + qL + l16) * DD + h * 64;
        bf16* CbH = ctx + (size_t)(b * TT + qH + l16) * DD + h * 64;
        #pragma unroll
        for (int gg = 0; gg < 4; ++gg) {
            alignas(8) bf16 oL[4], oH[4];
            #pragma unroll
            for (int r = 0; r < 4; ++r) {
                oL[r] = __float2bfloat16(caccL[gg][r] * invL);
                oH[r] = __float2bfloat16(caccH[gg][r] * invH);
            }
            *(short4v*)(CbL + gg * 16 + quad * 4) = *(const short4v*)oL;
            *(short4v*)(CbH + gg * 16 + quad * 4) = *(const short4v*)oH;
        }
    } else {
        // ------ FF2: xff = bigb @ Wff2t + bff2, 2-phase counted vmcnt ------
        const int wm = w >> 1, wn = w & 1;

        const int flat = half;
        const int c8 = flat & 7;
        const int j  = flat >> 3;
        const int jy = j >> 3;          // nxb = 8
        const int m0 = (c8 * 8 + jy) * 128;
        const int n0 = (j & 7) * 64;

        const int srow = lane >> 3;
        const int scol = ((lane & 7) ^ srow) * 8;

        const bf16* Ap = bigb  + (size_t)(m0 + w * 32 + srow) * FFD + scol;
        const bf16* Bp = Wff2t + (size_t)(n0 + w * 16 + srow) * FFD + scol;

        f32x4 acc[4][2] = {};

#define FSTAGE(bb, kk) do { \
        _Pragma("unroll") \
        for (int i = 0; i < 4; ++i) \
            async_copy16(Ap + (size_t)(i * 8) * FFD + (kk), \
                         smem + (bb) * 8192 + (w * 32 + i * 8) * 64); \
        _Pragma("unroll") \
        for (int i = 0; i < 2; ++i) \
            async_copy16(Bp + (size_t)(i * 8) * FFD + (kk), \
                         smem + 16384 + (bb) * 4096 + (w * 16 + i * 8) * 64); \
    } while (0)

        FSTAGE(0, 0);
        for (int t = 0; t < 32; ++t) {
            const int cur = t & 1;
            if (t < 31) {
                FSTAGE(cur ^ 1, (t + 1) * 64);
                asm volatile("s_waitcnt vmcnt(6)" ::: "memory");
            } else {
                asm volatile("s_waitcnt vmcnt(0)" ::: "memory");
            }
            __builtin_amdgcn_s_barrier();
            __builtin_amdgcn_sched_barrier(0);
            const bf16* AsB = smem + cur * 8192;
            const bf16* BsB = smem + 16384 + cur * 4096;
            __builtin_amdgcn_s_setprio(1);
            #pragma unroll
            for (int ks = 0; ks < 2; ++ks) {
                short8 af[4], bfr[2];
                #pragma unroll
                for (int mt = 0; mt < 4; ++mt) {
                    const int row = wm * 64 + mt * 16 + l16;
                    const int c   = ((ks * 4 + quad) ^ (row & 7)) * 16;
                    af[mt] = *(const short8*)((const char*)(AsB + row * 64) + c);
                }
                #pragma unroll
                for (int nt = 0; nt < 2; ++nt) {
                    const int col = wn * 32 + nt * 16 + l16;
                    const int c   = ((ks * 4 + quad) ^ (col & 7)) * 16;
                    bfr[nt] = *(const short8*)((const char*)(BsB + col * 64) + c);
                }
                #pragma unroll
                for (int mt = 0; mt < 4; ++mt)
                    #pragma unroll
                    for (int nt = 0; nt < 2; ++nt)
                        acc[mt][nt] = __builtin_amdgcn_mfma_f32_16x16x32_bf16(
                            af[mt], bfr[nt], acc[mt][nt], 0, 0, 0);
            }
            __builtin_amdgcn_s_setprio(0);
            asm volatile("" ::: "memory");
            __builtin_amdgcn_s_barrier();
        }
#undef FSTAGE

        const int crow0 = m0 + wm * 64 + quad * 4;
        const int ccol0 = n0 + wn * 32 + l16;
        #pragma unroll
        for (int nt = 0; nt < 2; ++nt) {
            const int col = ccol0 + nt * 16;
            const float bv = bff2[col];
            #pragma unroll
            for (int mt = 0; mt < 4; ++mt)
                #pragma unroll
                for (int r = 0; r < 4; ++r) {
                    const int row = crow0 + mt * 16 + r;
                    xffb[(size_t)row * DD + col] =
                        __float2bfloat16(acc[mt][nt][r] + bv);
                }
        }
    }
}

// ---------------------------------------------------------------------------
// Depthwise causal conv (k=15) + BN + swish, register sliding window v2:
// thread = 2 channels x 16 consecutive t. BN folded to s*a + c.
// ---------------------------------------------------------------------------
__global__ __launch_bounds__(256) void dwconv_kernel(const bf16* __restrict__ c1,
                                                     const float* __restrict__ dwk,
                                                     const float* __restrict__ dwb,
                                                     const float* __restrict__ bn_g,
                                                     const float* __restrict__ bn_b,
                                                     const float* __restrict__ bn_m,
                                                     const float* __restrict__ bn_v,
                                                     bf16* __restrict__ out) {
    const int C2 = 2 * DD;   // 1024
    const int lin = blockIdx.x * 256 + threadIdx.x;   // 512 chp * 512 chunks
    const int chp = lin & 511;
    const int ch  = chp << 1;
    const int tch = lin >> 9;          // wave-uniform
    const int row0 = tch << 4;         // global row (b*1024 + t), 16 rows
    const int t0   = row0 & (TT - 1);

    float w0[KW], w1[KW];
    #pragma unroll
    for (int i = 0; i < KW; ++i) {
        w0[i] = dwk[i * C2 + ch];
        w1[i] = dwk[i * C2 + ch + 1];
    }
    const float a0 = rsqrtf(bn_v[ch] + 1e-3f) * bn_g[ch];
    const float a1 = rsqrtf(bn_v[ch + 1] + 1e-3f) * bn_g[ch + 1];
    const float c0 = (dwb[ch] - bn_m[ch]) * a0 + bn_b[ch];
    const float c1v = (dwb[ch + 1] - bn_m[ch + 1]) * a1 + bn_b[ch + 1];

    float x0[30], x1[30];
    if (t0 >= KW - 1) {
        #pragma unroll
        for (int i = 0; i < 30; ++i) {
            unsigned u = *(const unsigned*)(c1 + (size_t)(row0 - (KW - 1) + i) * C2 + ch);
            x0[i] = bf2f(u & 0xffff);
            x1[i] = bf2f(u >> 16);
        }
    } else {   // t0 == 0: guard the causal left edge (zero pad)
        #pragma unroll
        for (int i = 0; i < 30; ++i) {
            unsigned u = 0;
            if (t0 - (KW - 1) + i >= 0)
                u = *(const unsigned*)(c1 + (size_t)(row0 - (KW - 1) + i) * C2 + ch);
            x0[i] = bf2f(u & 0xffff);
            x1[i] = bf2f(u >> 16);
        }
    }

    #pragma unroll
    for (int j = 0; j < 16; ++j) {
        float s0 = 0.f, s1 = 0.f;
        #pragma unroll
        for (int i = 0; i < KW; ++i) {
            s0 += x0[j + i] * w0[i];
            s1 += x1[j + i] * w1[i];
        }
        s0 = s0 * a0 + c0;
        s1 = s1 * a1 + c1v;
        s0 = s0 / (1.f + __expf(-s0));
        s1 = s1 / (1.f + __expf(-s1));
        alignas(4) bf16 ob[2] = {__float2bfloat16(s0), __float2bfloat16(s1)};
        *(unsigned*)(out + (size_t)(row0 + j) * C2 + ch) = *(const unsigned*)ob;
    }
}

// ---------------------------------------------------------------------------
extern "C" void kernel_launch(void* const* d_in, const int* in_sizes, int n_in,
                              void* d_out, int out_size, void* d_ws, size_t ws_size,
                              hipStream_t stream) {
    const float* x    = (const float*)d_in[0];
    const float* g1   = (const float*)d_in[1];
    const float* b1   = (const float*)d_in[2];
    const float* Wff1 = (const float*)d_in[3];
    const float* bff1 = (const float*)d_in[4];
    const float* Wff2 = (const float*)d_in[5];
    const float* bff2 = (const float*)d_in[6];
    const float* ga   = (const float*)d_in[7];
    const float* ba   = (const float*)d_in[8];
    const float* Wq   = (const float*)d_in[9];
    const float* bq   = (const float*)d_in[10];
    const float* Wk   = (const float*)d_in[11];
    const float* bk   = (const float*)d_in[12];
    const float* Wv   = (const float*)d_in[13];
    const float* bv   = (const float*)d_in[14];
    const float* Wo   = (const float*)d_in[15];
    const float* bo   = (const float*)d_in[16];
    const float* gc   = (const float*)d_in[17];
    const float* bc   = (const float*)d_in[18];
    const float* Wcp  = (const float*)d_in[19];
    const float* bcp  = (const float*)d_in[20];
    const float* dwk  = (const float*)d_in[21];
    const float* dwb  = (const float*)d_in[22];
    const float* bn_g = (const float*)d_in[23];
    const float* bn_b = (const float*)d_in[24];
    const float* bn_m = (const float*)d_in[25];
    const float* bn_v = (const float*)d_in[26];
    const float* Wco  = (const float*)d_in[27];
    const float* bco  = (const float*)d_in[28];
    const float* g2   = (const float*)d_in[29];
    const float* b2   = (const float*)d_in[30];
    const float* Wf1  = (const float*)d_in[31];
    const float* bf1  = (const float*)d_in[32];
    const float* Wf2  = (const float*)d_in[33];
    const float* bf2  = (const float*)d_in[34];

    float* out = (float*)d_out;

    // ---- workspace layout ----
    char* p = (char*)d_ws;
    bf16* lnb   = (bf16*)p;  p += (size_t)MR * DD * 2;
    bf16* lnab  = (bf16*)p;  p += (size_t)MR * DD * 2;
    bf16* qkvb  = (bf16*)p;  p += (size_t)MR * QKVN * 2;
    bf16* Vtb   = (bf16*)p;  p += (size_t)MR * DD * 2;
    bf16* ctxb  = (bf16*)p;  p += (size_t)MR * DD * 2;
    bf16* xffb  = (bf16*)p;  p += (size_t)MR * DD * 2;
    bf16* bigb  = (bf16*)p;  p += (size_t)MR * FFD * 2;
    bf16* c2b   = (bf16*)p;  p += (size_t)MR * 1024 * 2;
    bf16* Wff1t = (bf16*)p;  p += (size_t)FFD * DD * 2;
    bf16* Wff2t = (bf16*)p;  p += (size_t)DD * FFD * 2;
    bf16* Wqkvt = (bf16*)p;  p += (size_t)QKVN * DD * 2;
    bf16* Wot   = (bf16*)p;  p += (size_t)DD * DD * 2;
    bf16* Wcpt  = (bf16*)p;  p += (size_t)1024 * DD * 2;
    bf16* Wcot  = (bf16*)p;  p += (size_t)DD * 1024 * 2;
    bf16* Wf1t  = (bf16*)p;  p += (size_t)FFD * DD * 2;
    bf16* Wf2t  = (bf16*)p;  p += (size_t)DD * FFD * 2;
    float* bqkv = (float*)p; p += QKVN * 4;

    dim3 blk(256);

    PrepPack P;
    auto set = [&](int i, const float* s, bf16* d, int K, int N, float sc, int off) {
        P.src[i] = s; P.dst[i] = d; P.K[i] = K; P.scale[i] = sc; P.off[i] = off;
        int nt = N / 64, lg = 0; while ((1 << lg) < nt) ++lg; P.lgNT[i] = lg;
    };
    set(0, Wff1, Wff1t, DD,  FFD, 1.f,    0);
    set(1, Wff2, Wff2t, FFD, DD,  1.f,    256);
    set(2, Wq,   Wqkvt,                DD, DD, 0.125f, 512);
    set(3, Wk,   Wqkvt + (size_t)512 * DD,  DD, DD, 1.f, 576);
    set(4, Wv,   Wqkvt + (size_t)1024 * DD, DD, DD, 1.f, 640);
    set(5, Wo,   Wot,   DD,  DD,  1.f,    704);
    set(6, Wcp,  Wcpt,  DD,  1024, 1.f,   768);
    set(7, Wco,  Wcot,  1024, DD, 1.f,    896);
    set(8, Wf1,  Wf1t,  DD,  FFD, 1.f,    1024);
    set(9, Wf2,  Wf2t,  FFD, DD,  1.f,    1280);
    P.bq = bq; P.bk = bk; P.bv = bv; P.bdst = bqkv;
    P.x = x; P.g1 = g1; P.b1 = b1; P.ga = ga; P.ba = ba;
    P.o1 = lnb; P.o2 = lnab;

    // 1. prep: weight transposes + bias concat + dual LN (all independent)
    prep_kernel<<<dim3(1537 + MR / 4), blk, 0, stream>>>(P);
    // 2. fused FF1 + QKV, 256x256 ring-buffer tiles (FF1: 256, QKV: 192)
    gemm256_kernel<<<dim3(448), dim3(512), 0, stream>>>(
        lnb, Wff1t, bff1, bigb, lnab, Wqkvt, bqkv, qkvb, Vtb, 256);
    // 3. fused flash-attention + FF2 (parity-interleaved, FF2 2-phase)
    ff2attn_kernel<<<dim3(1024), blk, 0, stream>>>(
        qkvb, Vtb, ctxb, bigb, Wff2t, bff2, xffb);
    // 4+5. x1 = x + 0.5*xff + (ctx @ Wo + bo) -> fp32 out; lnc = LN(x1) -> lnb
    fusedln_kernel<8, 2><<<dim3(256), dim3(512), 0, stream>>>(
        ctxb, Wot, bo, x, xffb, 0.5f, out, gc, bc, lnb);
    // 6. c1 = gelu(lnc @ Wcp + bcp) -> bf16   (nxb = 8)
    bgemm_kernel<128, 2, 0, 1><<<dim3(8 * 64), blk, 0, stream>>>(
        lnb, Wcpt, bcp, nullptr, nullptr, 0.f, 1.f, bigb, 1024, DD, 8);
    // 7. c2 = swish(BN(dwconv(c1))) -> bf16   (16 t per thread)
    dwconv_kernel<<<dim3(MR * 512 / 16 / 256), blk, 0, stream>>>(
        bigb, dwk, dwb, bn_g, bn_b, bn_m, bn_v, c2b);
    // 8+9. x2 = x1 + (c2 @ Wco + bco) -> fp32 out (in-place); ln2 -> lnb
    fusedln_kernel<16, 1><<<dim3(256), dim3(512), 0, stream>>>(
        c2b, Wcot, bco, out, nullptr, 0.f, out, g2, b2, lnb);
    // 10. h2 = relu(ln2 @ Wf1 + bf1) -> bf16, same ring-buffer kernel
    gemm256_kernel<<<dim3(256), dim3(512), 0, stream>>>(
        lnb, Wf1t, bf1, bigb, nullptr, nullptr, nullptr, nullptr, nullptr, 256);
    // 11. out = x2 + (h2 @ Wf2 + bf2) -> fp32 d_out   (BN=64, nxb=8)
    bgemm_kernel<64, 0, 1, 0><<<dim3(8 * 64), blk, 0, stream>>>(
        bigb, Wf2t, bf2, out, nullptr, 0.f, 1.f, out, DD, FFD, 8);
}

// Round 9
// 358.587 us; speedup vs baseline: 1.0167x; 1.0167x over previous
//
#include <hip/hip_runtime.h>
#include <hip/hip_bf16.h>
#include <math.h>

#define BB 8
#define TT 1024
#define DD 512
#define FFD 2048
#define HH 8
#define HDD 64
#define KW 15
#define MR (BB*TT)   // 8192 rows
#define QKVN 1536

typedef __attribute__((ext_vector_type(8))) short short8;   // 8 bf16 = 4 VGPRs
typedef __attribute__((ext_vector_type(4))) short short4v;  // 8 bytes
typedef __attribute__((ext_vector_type(4))) float f32x4;
typedef __hip_bfloat16 bf16;

__device__ __forceinline__ float bf2f(unsigned u16) {
    return __uint_as_float(u16 << 16);
}

__device__ __forceinline__ void async_copy16(const void* g, void* l) {
    __builtin_amdgcn_global_load_lds(
        (const __attribute__((address_space(1))) void*)g,
        (__attribute__((address_space(3))) void*)l, 16, 0, 0);
}

__device__ __forceinline__ float gelu_exact(float v) {
    return 0.5f * v * (1.0f + erff(v * 0.70710678118654752f));
}

// ---------------------------------------------------------------------------
// Prep super-kernel: blocks 0..1535 weight transpose, 1536 bias concat,
// 1537..3584 dual LayerNorm (LN1+LNa share row stats). All independent.
// ---------------------------------------------------------------------------
struct PrepPack {
    const float* src[10];
    bf16*        dst[10];
    int          K[10];
    int          lgNT[10];
    float        scale[10];
    int          off[10];
    const float* bq; const float* bk; const float* bv;
    float*       bdst;
    const float* x;
    const float* g1; const float* b1; const float* ga; const float* ba;
    bf16* o1; bf16* o2;
};

__global__ __launch_bounds__(256) void prep_kernel(PrepPack P) {
    __shared__ alignas(16) bf16 T[64][72];
    const int bid = blockIdx.x;
    if (bid == 1536) {   // bias concat
        #pragma unroll
        for (int it = 0; it < 6; ++it) {
            int i = it * 256 + threadIdx.x;
            float v = i < 512 ? P.bq[i] * 0.125f
                              : (i < 1024 ? P.bk[i - 512] : P.bv[i - 1024]);
            P.bdst[i] = v;
        }
        return;
    }
    if (bid > 1536) {    // dual LN: 4 rows per block (wave per row)
        int wave = ((bid - 1537) * 256 + (int)threadIdx.x) >> 6;
        int lane = threadIdx.x & 63;
        const float* row = P.x + (size_t)wave * DD;
        float4 v0 = ((const float4*)row)[lane];
        float4 v1 = ((const float4*)row)[64 + lane];
        float s  = v0.x + v0.y + v0.z + v0.w + v1.x + v1.y + v1.z + v1.w;
        float ss = v0.x*v0.x + v0.y*v0.y + v0.z*v0.z + v0.w*v0.w
                 + v1.x*v1.x + v1.y*v1.y + v1.z*v1.z + v1.w*v1.w;
        #pragma unroll
        for (int off = 32; off >= 1; off >>= 1) {
            s  += __shfl_xor(s,  off, 64);
            ss += __shfl_xor(ss, off, 64);
        }
        float mean = s * (1.0f / DD);
        float var  = ss * (1.0f / DD) - mean * mean;
        float r    = rsqrtf(var + 1e-3f);
        float n0x = (v0.x - mean) * r, n0y = (v0.y - mean) * r,
              n0z = (v0.z - mean) * r, n0w = (v0.w - mean) * r;
        float n1x = (v1.x - mean) * r, n1y = (v1.y - mean) * r,
              n1z = (v1.z - mean) * r, n1w = (v1.w - mean) * r;
        {
            float4 g0 = ((const float4*)P.g1)[lane];
            float4 gg = ((const float4*)P.g1)[64 + lane];
            float4 b0 = ((const float4*)P.b1)[lane];
            float4 bb = ((const float4*)P.b1)[64 + lane];
            alignas(8) bf16 o0[4], o1[4];
            o0[0] = __float2bfloat16(n0x * g0.x + b0.x);
            o0[1] = __float2bfloat16(n0y * g0.y + b0.y);
            o0[2] = __float2bfloat16(n0z * g0.z + b0.z);
            o0[3] = __float2bfloat16(n0w * g0.w + b0.w);
            o1[0] = __float2bfloat16(n1x * gg.x + bb.x);
            o1[1] = __float2bfloat16(n1y * gg.y + bb.y);
            o1[2] = __float2bfloat16(n1z * gg.z + bb.z);
            o1[3] = __float2bfloat16(n1w * gg.w + bb.w);
            bf16* orow = P.o1 + (size_t)wave * DD;
            *(short4v*)(orow + lane * 4)       = *(const short4v*)o0;
            *(short4v*)(orow + 256 + lane * 4) = *(const short4v*)o1;
        }
        {
            float4 g0 = ((const float4*)P.ga)[lane];
            float4 gg = ((const float4*)P.ga)[64 + lane];
            float4 b0 = ((const float4*)P.ba)[lane];
            float4 bb = ((const float4*)P.ba)[64 + lane];
            alignas(8) bf16 o0[4], o1[4];
            o0[0] = __float2bfloat16(n0x * g0.x + b0.x);
            o0[1] = __float2bfloat16(n0y * g0.y + b0.y);
            o0[2] = __float2bfloat16(n0z * g0.z + b0.z);
            o0[3] = __float2bfloat16(n0w * g0.w + b0.w);
            o1[0] = __float2bfloat16(n1x * gg.x + bb.x);
            o1[1] = __float2bfloat16(n1y * gg.y + bb.y);
            o1[2] = __float2bfloat16(n1z * gg.z + bb.z);
            o1[3] = __float2bfloat16(n1w * gg.w + bb.w);
            bf16* orow = P.o2 + (size_t)wave * DD;
            *(short4v*)(orow + lane * 4)       = *(const short4v*)o0;
            *(short4v*)(orow + 256 + lane * 4) = *(const short4v*)o1;
        }
        return;
    }
    // weight transpose tile
    int e = 0;
    #pragma unroll
    for (int i = 1; i < 10; ++i) e = (bid >= P.off[i]) ? i : e;
    const float* W  = P.src[e];
    bf16*        Wt = P.dst[e];
    const int    K  = P.K[e];
    const int    lg = P.lgNT[e];
    const float  scale = P.scale[e];
    const int local = bid - P.off[e];
    const int bx = local & ((1 << lg) - 1);
    const int by = local >> lg;
    const int k0 = by * 64;
    const int n0 = bx * 64;
    const int N  = (1 << lg) * 64;
    const int tid = threadIdx.x;
    #pragma unroll
    for (int it = 0; it < 4; ++it) {
        int lin = it * 256 + tid;
        int kl  = lin >> 4;
        int nq  = (lin & 15) * 4;
        float4 v = *(const float4*)(W + (size_t)(k0 + kl) * N + n0 + nq);
        T[nq + 0][kl] = __float2bfloat16(v.x * scale);
        T[nq + 1][kl] = __float2bfloat16(v.y * scale);
        T[nq + 2][kl] = __float2bfloat16(v.z * scale);
        T[nq + 3][kl] = __float2bfloat16(v.w * scale);
    }
    __syncthreads();
    #pragma unroll
    for (int it = 0; it < 4; ++it) {
        int lin = it * 256 + tid;
        int nl  = lin >> 4;
        int kq  = (lin & 15) * 4;
        *(short4v*)(Wt + (size_t)(n0 + nl) * K + k0 + kq) = *(const short4v*)&T[nl][kq];
    }
}

// ---------------------------------------------------------------------------
// Generic bf16 MFMA GEMM — 2-phase double-buffered pipeline (counted vmcnt).
// OUTMODE: 0 fp32, 1 bf16*oscale. RESMODE: 0/1 (+fp32 res1)
// /2 (+res1 + s2*bf16 res2).
// ---------------------------------------------------------------------------
template<int BN, int OP, int RESMODE, int OUTMODE>
__global__ __launch_bounds__(256) void bgemm_kernel(
    const bf16* __restrict__ A,
    const bf16* __restrict__ Bt,
    const float* __restrict__ bias,
    const float* __restrict__ res1,
    const bf16* __restrict__ res2,
    float s2, float oscale,
    void* __restrict__ Cout,
    int N, int Kd, int nxb)
{
    constexpr int NT = BN / 32;
    constexpr int S  = 4 + BN / 32;    // async issues per stage per thread
    __shared__ alignas(16) bf16 As[2][128][64];
    __shared__ alignas(16) bf16 Bs[2][BN][64];
    const int tid  = threadIdx.x;
    const int w    = tid >> 6;
    const int lane = tid & 63;
    const int quad = lane >> 4;
    const int l16  = lane & 15;
    const int wm   = w >> 1, wn = w & 1;

    const int flat = blockIdx.x;
    const int c8   = flat & 7;
    const int j    = flat >> 3;
    const int jy   = j / nxb;
    const int m0   = (c8 * 8 + jy) * 128;
    const int n0   = (j - jy * nxb) * BN;

    const int srow = lane >> 3;
    const int scol = ((lane & 7) ^ srow) * 8;

    const bf16* Ap = A  + (size_t)(m0 + w * 32 + srow) * Kd + scol;
    const bf16* Bp = Bt + (size_t)(n0 + w * (BN / 4) + srow) * Kd + scol;

    f32x4 acc[4][NT] = {};
    const int nk = Kd >> 6;

#define BSTAGE(bb, kk) do { \
        _Pragma("unroll") \
        for (int i = 0; i < 4; ++i) \
            async_copy16(Ap + (size_t)(i * 8) * Kd + (kk), &As[bb][w * 32 + i * 8][0]); \
        _Pragma("unroll") \
        for (int i = 0; i < BN / 32; ++i) \
            async_copy16(Bp + (size_t)(i * 8) * Kd + (kk), &Bs[bb][w * (BN / 4) + i * 8][0]); \
    } while (0)

    BSTAGE(0, 0);
    for (int t = 0; t < nk; ++t) {
        const int cur = t & 1;
        if (t + 1 < nk) {
            BSTAGE(cur ^ 1, (t + 1) * 64);
            if constexpr (S == 6) asm volatile("s_waitcnt vmcnt(6)" ::: "memory");
            else                  asm volatile("s_waitcnt vmcnt(8)" ::: "memory");
        } else {
            asm volatile("s_waitcnt vmcnt(0)" ::: "memory");
        }
        __builtin_amdgcn_s_barrier();
        __builtin_amdgcn_sched_barrier(0);
        __builtin_amdgcn_s_setprio(1);
        #pragma unroll
        for (int ks = 0; ks < 2; ++ks) {
            short8 af[4], bfr[NT];
            #pragma unroll
            for (int mt = 0; mt < 4; ++mt) {
                const int row = wm * 64 + mt * 16 + l16;
                const int c   = ((ks * 4 + quad) ^ (row & 7)) * 16;
                af[mt] = *(const short8*)((const char*)&As[cur][row][0] + c);
            }
            #pragma unroll
            for (int nt = 0; nt < NT; ++nt) {
                const int col = wn * (BN / 2) + nt * 16 + l16;
                const int c   = ((ks * 4 + quad) ^ (col & 7)) * 16;
                bfr[nt] = *(const short8*)((const char*)&Bs[cur][col][0] + c);
            }
            #pragma unroll
            for (int mt = 0; mt < 4; ++mt)
                #pragma unroll
                for (int nt = 0; nt < NT; ++nt)
                    acc[mt][nt] = __builtin_amdgcn_mfma_f32_16x16x32_bf16(
                        af[mt], bfr[nt], acc[mt][nt], 0, 0, 0);
        }
        __builtin_amdgcn_s_setprio(0);
        asm volatile("" ::: "memory");
        __builtin_amdgcn_s_barrier();
    }
#undef BSTAGE

    const int crow0 = m0 + wm * 64 + quad * 4;
    const int ccol0 = n0 + wn * (BN / 2) + l16;
    #pragma unroll
    for (int nt = 0; nt < NT; ++nt) {
        const int col = ccol0 + nt * 16;
        const float bv = bias[col];
        #pragma unroll
        for (int mt = 0; mt < 4; ++mt) {
            #pragma unroll
            for (int r = 0; r < 4; ++r) {
                const int row = crow0 + mt * 16 + r;
                const size_t off = (size_t)row * N + col;
                float o = acc[mt][nt][r] + bv;
                if (OP == 1)      o = fmaxf(o, 0.f);
                else if (OP == 2) o = gelu_exact(o);
                if (RESMODE >= 1) o += res1[off];
                if (RESMODE == 2) o += s2 * __bfloat162float(res2[off]);
                if (OUTMODE == 0) ((float*)Cout)[off] = o;
                else              ((bf16*)Cout)[off]  = __float2bfloat16(o * oscale);
            }
        }
    }
}

// ---------------------------------------------------------------------------
// Fused full-row GEMM + residuals + LayerNorm (replaces steps 4+5 and 8+9).
// Tile BM=32 x BN=512 (full row width). v2: bgemm-style counted-vmcnt
// double-buffer — stage(t+1) issued BEFORE compute(t), s_waitcnt vmcnt(8)
// (waves 0-3 have 9 loads/stage: drains all 9 old + 1 new; waves 4-7 have
// 8: drains exactly the old 8), two barriers per tile, setprio around MFMA.
// ---------------------------------------------------------------------------
template<int NK, int RESMODE>
__global__ __launch_bounds__(512, 1) void fusedln_kernel(
    const bf16* __restrict__ A, const bf16* __restrict__ Bt,
    const float* __restrict__ bias,
    const float* __restrict__ res1, const bf16* __restrict__ res2, float s2,
    float* __restrict__ outF,
    const float* __restrict__ g, const float* __restrict__ bb,
    bf16* __restrict__ lnout)
{
    constexpr int Kd = NK * 64;
    __shared__ alignas(16) char lds[2 * 69632];   // buf: B[512][128B] + A[32][128B]
    const int tid  = threadIdx.x;
    const int w    = tid >> 6;
    const int lane = tid & 63;
    const int quad = lane >> 4;
    const int l16  = lane & 15;
    const int wm   = w >> 2, wn = w & 3;
    const int m0   = (int)blockIdx.x * 32;

    const int srow = lane >> 3;
    const int swz  = ((lane & 7) ^ srow) * 8;   // pre-swizzled source chunk
    const bf16* BpS = Bt + (size_t)(w * 64 + srow) * Kd + swz;
    const bf16* ApS = A  + (size_t)(m0 + (w & 3) * 8 + srow) * Kd + swz;

#define FSTG(kc, base) do { \
        _Pragma("unroll") \
        for (int i = 0; i < 8; ++i) \
            async_copy16(BpS + (size_t)(i * 8) * Kd + (kc), \
                         lds + (base) + (w * 64 + i * 8) * 128); \
        if (w < 4) \
            async_copy16(ApS + (kc), \
                         lds + (base) + 65536 + ((w & 3) * 8) * 128); \
    } while (0)

    const int cxa0 = ((quad)     ^ (l16 & 7)) * 16;
    const int cxa1 = ((4 + quad) ^ (l16 & 7)) * 16;

    f32x4 acc[8] = {};

    FSTG(0, 0);
    for (int t = 0; t < NK; ++t) {
        const int cb = (t & 1) * 69632;
        if (t + 1 < NK) {
            FSTG((t + 1) * 64, ((t + 1) & 1) * 69632);
            asm volatile("s_waitcnt vmcnt(8)" ::: "memory");
        } else {
            asm volatile("s_waitcnt vmcnt(0)" ::: "memory");
        }
        __builtin_amdgcn_s_barrier();
        __builtin_amdgcn_sched_barrier(0);
        __builtin_amdgcn_s_setprio(1);

        const char* abase = lds + cb + 65536 + (wm * 16 + l16) * 128;
        short8 a0 = *(const short8*)(abase + cxa0);
        short8 a1 = *(const short8*)(abase + cxa1);
        #pragma unroll
        for (int nt = 0; nt < 8; ++nt) {
            const char* bbase = lds + cb + (wn * 128 + nt * 16 + l16) * 128;
            short8 b0 = *(const short8*)(bbase + cxa0);
            short8 b1 = *(const short8*)(bbase + cxa1);
            acc[nt] = __builtin_amdgcn_mfma_f32_16x16x32_bf16(a0, b0, acc[nt], 0, 0, 0);
            acc[nt] = __builtin_amdgcn_mfma_f32_16x16x32_bf16(a1, b1, acc[nt], 0, 0, 0);
        }
        __builtin_amdgcn_s_setprio(0);
        asm volatile("" ::: "memory");
        __builtin_amdgcn_s_barrier();
    }
#undef FSTG

    // ---- epilogue: residuals + fp32 store + in-register LN ----
    const int row0 = m0 + wm * 16 + quad * 4;
    float val[8][4];
    float s[4] = {0.f, 0.f, 0.f, 0.f}, ss[4] = {0.f, 0.f, 0.f, 0.f};
    #pragma unroll
    for (int nt = 0; nt < 8; ++nt) {
        const int col = wn * 128 + nt * 16 + l16;
        const float bv = bias[col];
        #pragma unroll
        for (int r = 0; r < 4; ++r) {
            const size_t off = (size_t)(row0 + r) * DD + col;
            float o = acc[nt][r] + bv;
            if (RESMODE >= 1) o += res1[off];
            if (RESMODE == 2) o += s2 * __bfloat162float(res2[off]);
            outF[off] = o;
            val[nt][r] = o;
            s[r]  += o;
            ss[r] += o * o;
        }
    }
    #pragma unroll
    for (int off = 8; off >= 1; off >>= 1) {
        #pragma unroll
        for (int r = 0; r < 4; ++r) {
            s[r]  += __shfl_xor(s[r],  off, 64);
            ss[r] += __shfl_xor(ss[r], off, 64);
        }
    }
    __syncthreads();
    float2* red = (float2*)lds;    // [wn 4][row 32]
    if (l16 == 0) {
        #pragma unroll
        for (int r = 0; r < 4; ++r) {
            float2 v; v.x = s[r]; v.y = ss[r];
            red[wn * 32 + (wm * 16 + quad * 4 + r)] = v;
        }
    }
    __syncthreads();
    float mean[4], rstd[4];
    #pragma unroll
    for (int r = 0; r < 4; ++r) {
        float a = 0.f, b2 = 0.f;
        #pragma unroll
        for (int q = 0; q < 4; ++q) {
            float2 v = red[q * 32 + (wm * 16 + quad * 4 + r)];
            a += v.x; b2 += v.y;
        }
        const float m = a * (1.0f / DD);
        const float var = b2 * (1.0f / DD) - m * m;
        mean[r] = m;
        rstd[r] = rsqrtf(var + 1e-3f);
    }
    #pragma unroll
    for (int nt = 0; nt < 8; ++nt) {
        const int col = wn * 128 + nt * 16 + l16;
        const float gv = g[col], bv2 = bb[col];
        #pragma unroll
        for (int r = 0; r < 4; ++r) {
            const size_t off = (size_t)(row0 + r) * DD + col;
            lnout[off] = __float2bfloat16(
                (val[nt][r] - mean[r]) * rstd[r] * gv + bv2);
        }
    }
}

// ---------------------------------------------------------------------------
// 256x256-tile GEMM (K=512), 512 threads = 8 waves, v5 (best measured): ONE
// barrier + one compiler-scheduled compute block per K-tile.
// LDS: 2 x 64KB buffers, 4 regions [128 rows][128B] each, XOR chunk swizzle
// via pre-swizzled global source (0-conflict, round-4 verified).
//   blocks 0..nffblk-1 : out = relu(Aff @ Btff^T + biasff) -> bf16 [8192,2048]
//   blocks >= nffblk   : qkv job (Q/K -> qkvb, V -> Vtb transposed)
// ---------------------------------------------------------------------------
__global__ __launch_bounds__(512, 2) void gemm256_kernel(
    const bf16* __restrict__ Aff, const bf16* __restrict__ Btff,
    const float* __restrict__ biasff, bf16* __restrict__ outff,
    const bf16* __restrict__ Aqk, const bf16* __restrict__ Btqk,
    const float* __restrict__ biasqk, bf16* __restrict__ qkvb,
    bf16* __restrict__ Vtb, int nffblk)
{
    __shared__ alignas(16) char lds[131072];
    const int tid  = threadIdx.x;
    const int w    = tid >> 6;
    const int lane = tid & 63;
    const int quad = lane >> 4;
    const int l16  = lane & 15;
    const int ms   = w >> 2, ns = w & 3;

    const bool jobq = (int)blockIdx.x >= nffblk;
    const int  flat = jobq ? (int)blockIdx.x - nffblk : (int)blockIdx.x;
    const int  nxb  = jobq ? 6 : 8;
    const bf16* A   = jobq ? Aqk : Aff;
    const bf16* Bt  = jobq ? Btqk : Btff;
    const float* bias = jobq ? biasqk : biasff;

    const int c8 = flat & 7;
    const int j  = flat >> 3;
    const int jy = j / nxb;
    const int m0 = (c8 * 4 + jy) * 256;
    const int n0 = (j - jy * nxb) * 256;

    const int srow = lane >> 3;
    const int swz  = ((lane & 7) ^ srow) * 8;   // element offset in row
    const bf16* ApS = A  + (size_t)(m0 + w * 16 + srow) * DD + swz;
    const bf16* BpS = Bt + (size_t)(n0 + w * 16 + srow) * DD + swz;

    // region byte bases within a buffer: A0=0, A1=16384, B0=32768, B1=49152
#define STG_A(half, kc, nbase) do { \
        async_copy16(ApS + (size_t)((half) * 128) * DD + (kc), \
                     lds + (nbase) + (half) * 16384 + (w * 16) * 128); \
        async_copy16(ApS + (size_t)((half) * 128 + 8) * DD + (kc), \
                     lds + (nbase) + (half) * 16384 + (w * 16 + 8) * 128); \
    } while (0)
#define STG_B(half, kc, nbase) do { \
        async_copy16(BpS + (size_t)((half) * 128) * DD + (kc), \
                     lds + (nbase) + 32768 + (half) * 16384 + (w * 16) * 128); \
        async_copy16(BpS + (size_t)((half) * 128 + 8) * DD + (kc), \
                     lds + (nbase) + 32768 + (half) * 16384 + (w * 16 + 8) * 128); \
    } while (0)

    const int cx0  = ((quad)     ^ (l16 & 7)) * 16;   // ks=0 chunk byte
    const int cx1  = ((4 + quad) ^ (l16 & 7)) * 16;   // ks=1 chunk byte
    const int arow = (ms * 64 + l16) * 128;
    const int brow = (ns * 32 + l16) * 128;

    f32x4 acc[8][4] = {};

    // prologue: tile0 -> buffer 0
    STG_A(0, 0, 0); STG_B(0, 0, 0); STG_B(1, 0, 0); STG_A(1, 0, 0);
    asm volatile("s_waitcnt vmcnt(0)" ::: "memory");

    for (int t = 0; t < 8; ++t) {
        const int cb = (t & 1) * 65536;
        const int nb = cb ^ 65536;

        asm volatile("" ::: "memory");
        __builtin_amdgcn_s_barrier();
        __builtin_amdgcn_sched_barrier(0);

        // stage next tile (data protected by next iteration's satisfied vmcnt)
        if (t < 7) {
            const int kn = (t + 1) * 64;
            STG_A(0, kn, nb); STG_B(0, kn, nb);
            STG_B(1, kn, nb); STG_A(1, kn, nb);
        }

        // ---- compute tile t: 8 B-reads (held) + 2x8 A-reads + 64 MFMA ----
        short8 fbv[2][2][2];   // [QN][nt][ks]
        #pragma unroll
        for (int QN = 0; QN < 2; ++QN)
            #pragma unroll
            for (int nt = 0; nt < 2; ++nt) {
                const char* bbase = lds + cb + 32768 + QN * 16384 + brow + nt * 2048;
                fbv[QN][nt][0] = *(const short8*)(bbase + cx0);
                fbv[QN][nt][1] = *(const short8*)(bbase + cx1);
            }
        #pragma unroll
        for (int QM = 0; QM < 2; ++QM) {
            short8 fav[4][2];
            #pragma unroll
            for (int mt = 0; mt < 4; ++mt) {
                const char* abase = lds + cb + QM * 16384 + arow + mt * 2048;
                fav[mt][0] = *(const short8*)(abase + cx0);
                fav[mt][1] = *(const short8*)(abase + cx1);
            }
            #pragma unroll
            for (int QN = 0; QN < 2; ++QN)
                #pragma unroll
                for (int mt = 0; mt < 4; ++mt)
                    #pragma unroll
                    for (int nt = 0; nt < 2; ++nt) {
                        acc[QM * 4 + mt][QN * 2 + nt] =
                            __builtin_amdgcn_mfma_f32_16x16x32_bf16(
                                fav[mt][0], fbv[QN][nt][0],
                                acc[QM * 4 + mt][QN * 2 + nt], 0, 0, 0);
                        acc[QM * 4 + mt][QN * 2 + nt] =
                            __builtin_amdgcn_mfma_f32_16x16x32_bf16(
                                fav[mt][1], fbv[QN][nt][1],
                                acc[QM * 4 + mt][QN * 2 + nt], 0, 0, 0);
                    }
        }

        // satisfied by ~one full tile of slack; protects nb for tile t+1
        asm volatile("s_waitcnt vmcnt(0)" ::: "memory");
    }
#undef STG_A
#undef STG_B

    // epilogue: frag (QM,mt) x (QN,nt); row = m0+QM*128+ms*64+mt*16+quad*4+r,
    // col = n0+QN*128+ns*32+nt*16+l16
    #pragma unroll
    for (int QN = 0; QN < 2; ++QN) {
        #pragma unroll
        for (int nt = 0; nt < 2; ++nt) {
            const int col = n0 + QN * 128 + ns * 32 + nt * 16 + l16;
            const float bv = bias[col];
            #pragma unroll
            for (int QM = 0; QM < 2; ++QM) {
                #pragma unroll
                for (int mt = 0; mt < 4; ++mt) {
                    const f32x4 av = acc[QM * 4 + mt][QN * 2 + nt];
                    const int rowt = m0 + QM * 128 + ms * 64 + mt * 16 + quad * 4;
                    if (jobq) {
                        alignas(8) bf16 o4[4];
                        #pragma unroll
                        for (int r = 0; r < 4; ++r)
                            o4[r] = __float2bfloat16(av[r] + bv);
                        if (col < 1024) {
                            #pragma unroll
                            for (int r = 0; r < 4; ++r)
                                qkvb[(size_t)(rowt + r) * QKVN + col] = o4[r];
                        } else {
                            const int dg  = col - 1024;
                            const int bbk = rowt >> 10, t0 = rowt & 1023;
                            const int bh2 = bbk * 8 + (dg >> 6), d = dg & 63;
                            *(short4v*)(Vtb + ((size_t)bh2 * 64 + d) * TT + t0) =
                                *(const short4v*)o4;
                        }
                    } else {
                        #pragma unroll
                        for (int r = 0; r < 4; ++r) {
                            const float o = fmaxf(av[r] + bv, 0.f);
                            outff[(size_t)(rowt + r) * FFD + col] =
                                __float2bfloat16(o);
                        }
                    }
                }
            }
        }
    }
}

// ---------------------------------------------------------------------------
// Fused FF2 + flash-attention super-kernel. Parity-interleaved: even blocks
// = attention (512), odd blocks = FF2 (512). FF2 is 2-phase double-buffered
// (counted vmcnt(6)). 48 KB LDS union -> 3 blocks/CU. Attention MFMA
// clusters wrapped in setprio(1) (T5).
// ---------------------------------------------------------------------------
__global__ __launch_bounds__(256) void ff2attn_kernel(
    const bf16* __restrict__ QKV, const bf16* __restrict__ Vt,
    bf16* __restrict__ ctx,
    const bf16* __restrict__ bigb, const bf16* __restrict__ Wff2t,
    const float* __restrict__ bff2, bf16* __restrict__ xffb)
{
    __shared__ alignas(16) bf16 smem[24576];   // 48 KB
    const int tid  = threadIdx.x;
    const int w    = tid >> 6;
    const int lane = tid & 63;
    const int quad = lane >> 4;
    const int l16  = lane & 15;
    const int half = (int)blockIdx.x >> 1;

    if ((blockIdx.x & 1) == 0) {
        // ---------------- flash attention v4 ----------------
        typedef bf16 (*tile_t)[64][64];
        tile_t Ks = (tile_t)smem;                    // Ks[2][64][64]
        tile_t Vs = (tile_t)(smem + 2 * 64 * 64);    // Vs[2][64][64]
        const int bh = half & 63;
        const int bi = 7 - (half >> 6);              // long blocks first
        const int b = bh >> 3, h = bh & 7;

        const bf16* Qg = QKV + (size_t)(b * TT) * QKVN + h * 64;
        const bf16* Kg = QKV + (size_t)(b * TT) * QKVN + 512 + h * 64;
        const bf16* Vg = Vt  + (size_t)bh * 64 * TT;

        const int qL = bi * 128 + w * 16;
        const int qH = qL + 64;
        short8 qfL0 = *(const short8*)(Qg + (size_t)(qL + l16) * QKVN + quad * 8);
        short8 qfL1 = *(const short8*)(Qg + (size_t)(qL + l16) * QKVN + 32 + quad * 8);
        short8 qfH0 = *(const short8*)(Qg + (size_t)(qH + l16) * QKVN + quad * 8);
        short8 qfH1 = *(const short8*)(Qg + (size_t)(qH + l16) * QKVN + 32 + quad * 8);

        const int sgrow  = lane >> 3;
        const int sgchnk = lane & 7;

        f32x4 caccL[4] = {}, caccH[4] = {};
        float lL = 0.f, lH = 0.f;
        const int prow_base = ((l16 >> 2) << 3) + (l16 & 3);
        const int smax = 2 * bi + 1;

        #pragma unroll
        for (int i = 0; i < 2; ++i) {
            const int rowbase = w * 8 + i * 32;
            const int row = rowbase + sgrow;
            const int fR = (row & 3) | (((row >> 3) & 1) << 2);
            const int sc = sgchnk ^ fR;
            async_copy16(Kg + (size_t)row * QKVN + sc * 8, &Ks[0][rowbase][0]);
            async_copy16(Vg + (size_t)row * TT + sc * 8,   &Vs[0][rowbase][0]);
        }

        int buf = 0;
        for (int s = 0; s <= smax; ++s) {
            __syncthreads();
            if (s < smax) {
                const int kn = (s + 1) * 64;
                #pragma unroll
                for (int i = 0; i < 2; ++i) {
                    const int rowbase = w * 8 + i * 32;
                    const int row = rowbase + sgrow;
                    const int fR = (row & 3) | (((row >> 3) & 1) << 2);
                    const int sc = sgchnk ^ fR;
                    async_copy16(Kg + (size_t)(kn + row) * QKVN + sc * 8,
                                 &Ks[buf ^ 1][rowbase][0]);
                    async_copy16(Vg + (size_t)row * TT + kn + sc * 8,
                                 &Vs[buf ^ 1][rowbase][0]);
                }
            }
            const int k0 = s * 64;
            const bool doL = (s < smax);

            f32x4 sTL[4], sTH[4];
            __builtin_amdgcn_s_setprio(1);
            #pragma unroll
            for (int s4 = 0; s4 < 4; ++s4) {
                const int prow = prow_base + (s4 >> 1) * 32 + (s4 & 1) * 4;
                const int fR = (prow & 3) | (((prow >> 3) & 1) << 2);
                short8 ka = *(const short8*)&Ks[buf][prow][(quad ^ fR) * 8];
                short8 kb = *(const short8*)&Ks[buf][prow][((4 + quad) ^ fR) * 8];
                f32x4 zH = {0.f, 0.f, 0.f, 0.f};
                zH = __builtin_amdgcn_mfma_f32_16x16x32_bf16(ka, qfH0, zH, 0, 0, 0);
                sTH[s4] = __builtin_amdgcn_mfma_f32_16x16x32_bf16(kb, qfH1, zH, 0, 0, 0);
                if (doL) {
                    f32x4 zL = {0.f, 0.f, 0.f, 0.f};
                    zL = __builtin_amdgcn_mfma_f32_16x16x32_bf16(ka, qfL0, zL, 0, 0, 0);
                    sTL[s4] = __builtin_amdgcn_mfma_f32_16x16x32_bf16(kb, qfL1, zL, 0, 0, 0);
                }
            }
            __builtin_amdgcn_s_setprio(0);

            alignas(16) bf16 pbH[16], pbL[16];
            if (s == smax) {
                const int qg = qH + l16;
                #pragma unroll
                for (int s4 = 0; s4 < 4; ++s4)
                    #pragma unroll
                    for (int r = 0; r < 4; ++r) {
                        const int key = k0 + (s4 >> 1) * 32 + quad * 8 + (s4 & 1) * 4 + r;
                        const float p = (key <= qg) ? __expf(sTH[s4][r]) : 0.f;
                        lH += p;
                        pbH[s4 * 4 + r] = __float2bfloat16(p);
                    }
            } else {
                #pragma unroll
                for (int s4 = 0; s4 < 4; ++s4)
                    #pragma unroll
                    for (int r = 0; r < 4; ++r) {
                        const float p = __expf(sTH[s4][r]);
                        lH += p;
                        pbH[s4 * 4 + r] = __float2bfloat16(p);
                    }
            }
            if (doL) {
                if (s == smax - 1) {
                    const int qg = qL + l16;
                    #pragma unroll
                    for (int s4 = 0; s4 < 4; ++s4)
                        #pragma unroll
                        for (int r = 0; r < 4; ++r) {
                            const int key = k0 + (s4 >> 1) * 32 + quad * 8 + (s4 & 1) * 4 + r;
                            const float p = (key <= qg) ? __expf(sTL[s4][r]) : 0.f;
                            lL += p;
                            pbL[s4 * 4 + r] = __float2bfloat16(p);
                        }
                } else {
                    #pragma unroll
                    for (int s4 = 0; s4 < 4; ++s4)
                        #pragma unroll
                        for (int r = 0; r < 4; ++r) {
                            const float p = __expf(sTL[s4][r]);
                            lL += p;
                            pbL[s4 * 4 + r] = __float2bfloat16(p);
                        }
                }
            }
            const short8 pfH0 = *(const short8*)&pbH[0];
            const short8 pfH1 = *(const short8*)&pbH[8];
            const short8 pfL0 = *(const short8*)&pbL[0];
            const short8 pfL1 = *(const short8*)&pbL[8];

            __builtin_amdgcn_s_setprio(1);
            #pragma unroll
            for (int gg = 0; gg < 4; ++gg) {
                const int vrow = gg * 16 + l16;
                const int fR = (vrow & 3) | (((vrow >> 3) & 1) << 2);
                short8 va = *(const short8*)&Vs[buf][vrow][(quad ^ fR) * 8];
                short8 vb = *(const short8*)&Vs[buf][vrow][((4 + quad) ^ fR) * 8];
                caccH[gg] = __builtin_amdgcn_mfma_f32_16x16x32_bf16(va, pfH0, caccH[gg], 0, 0, 0);
                caccH[gg] = __builtin_amdgcn_mfma_f32_16x16x32_bf16(vb, pfH1, caccH[gg], 0, 0, 0);
                if (doL) {
                    caccL[gg] = __builtin_amdgcn_mfma_f32_16x16x32_bf16(va, pfL0, caccL[gg], 0, 0, 0);
                    caccL[gg] = __builtin_amdgcn_mfma_f32_16x16x32_bf16(vb, pfL1, caccL[gg], 0, 0, 0);
                }
            }
            __builtin_amdgcn_s_setprio(0);
            buf ^= 1;
        }

        lL += __shfl_xor(lL, 16, 64);
        lL += __shfl_xor(lL, 32, 64);
        lH += __shfl_xor(lH, 16, 64);
        lH += __shfl_xor(lH, 32, 64);
        const float invL = 1.0f / lL;
        const float invH = 1.0f / lH;

        bf16* CbL = ctx + (size_t)(b * TT + qL + l16) * DD + h * 64;
        bf16* CbH = ctx + (size_t)(b * TT + qH + l16) * DD + h * 64;
        #pragma unroll
        for (int gg = 0; gg < 4; ++gg) {
            alignas(8) bf16 oL[4], oH[4];
            #pragma unroll
            for (int r = 0; r < 4; ++r) {
                oL[r] = __float2bfloat16(caccL[gg][r] * invL);
                oH[r] = __float2bfloat16(caccH[gg][r] * invH);
            }
            *(short4v*)(CbL + gg * 16 + quad * 4) = *(const short4v*)oL;
            *(short4v*)(CbH + gg * 16 + quad * 4) = *(const short4v*)oH;
        }
    } else {
        // ------ FF2: xff = bigb @ Wff2t + bff2, 2-phase counted vmcnt ------
        const int wm = w >> 1, wn = w & 1;

        const int flat = half;
        const int c8 = flat & 7;
        const int j  = flat >> 3;
        const int jy = j >> 3;          // nxb = 8
        const int m0 = (c8 * 8 + jy) * 128;
        const int n0 = (j & 7) * 64;

        const int srow = lane >> 3;
        const int scol = ((lane & 7) ^ srow) * 8;

        const bf16* Ap = bigb  + (size_t)(m0 + w * 32 + srow) * FFD + scol;
        const bf16* Bp = Wff2t + (size_t)(n0 + w * 16 + srow) * FFD + scol;

        f32x4 acc[4][2] = {};

#define FSTAGE(bb, kk) do { \
        _Pragma("unroll") \
        for (int i = 0; i < 4; ++i) \
            async_copy16(Ap + (size_t)(i * 8) * FFD + (kk), \
                         smem + (bb) * 8192 + (w * 32 + i * 8) * 64); \
        _Pragma("unroll") \
        for (int i = 0; i < 2; ++i) \
            async_copy16(Bp + (size_t)(i * 8) * FFD + (kk), \
                         smem + 16384 + (bb) * 4096 + (w * 16 + i * 8) * 64); \
    } while (0)

        FSTAGE(0, 0);
        for (int t = 0; t < 32; ++t) {
            const int cur = t & 1;
            if (t < 31) {
                FSTAGE(cur ^ 1, (t + 1) * 64);
                asm volatile("s_waitcnt vmcnt(6)" ::: "memory");
            } else {
                asm volatile("s_waitcnt vmcnt(0)" ::: "memory");
            }
            __builtin_amdgcn_s_barrier();
            __builtin_amdgcn_sched_barrier(0);
            const bf16* AsB = smem + cur * 8192;
            const bf16* BsB = smem + 16384 + cur * 4096;
            __builtin_amdgcn_s_setprio(1);
            #pragma unroll
            for (int ks = 0; ks < 2; ++ks) {
                short8 af[4], bfr[2];
                #pragma unroll
                for (int mt = 0; mt < 4; ++mt) {
                    const int row = wm * 64 + mt * 16 + l16;
                    const int c   = ((ks * 4 + quad) ^ (row & 7)) * 16;
                    af[mt] = *(const short8*)((const char*)(AsB + row * 64) + c);
                }
                #pragma unroll
                for (int nt = 0; nt < 2; ++nt) {
                    const int col = wn * 32 + nt * 16 + l16;
                    const int c   = ((ks * 4 + quad) ^ (col & 7)) * 16;
                    bfr[nt] = *(const short8*)((const char*)(BsB + col * 64) + c);
                }
                #pragma unroll
                for (int mt = 0; mt < 4; ++mt)
                    #pragma unroll
                    for (int nt = 0; nt < 2; ++nt)
                        acc[mt][nt] = __builtin_amdgcn_mfma_f32_16x16x32_bf16(
                            af[mt], bfr[nt], acc[mt][nt], 0, 0, 0);
            }
            __builtin_amdgcn_s_setprio(0);
            asm volatile("" ::: "memory");
            __builtin_amdgcn_s_barrier();
        }
#undef FSTAGE

        const int crow0 = m0 + wm * 64 + quad * 4;
        const int ccol0 = n0 + wn * 32 + l16;
        #pragma unroll
        for (int nt = 0; nt < 2; ++nt) {
            const int col = ccol0 + nt * 16;
            const float bv = bff2[col];
            #pragma unroll
            for (int mt = 0; mt < 4; ++mt)
                #pragma unroll
                for (int r = 0; r < 4; ++r) {
                    const int row = crow0 + mt * 16 + r;
                    xffb[(size_t)row * DD + col] =
                        __float2bfloat16(acc[mt][nt][r] + bv);
                }
        }
    }
}

// ---------------------------------------------------------------------------
// Depthwise causal conv (k=15) + BN + swish, register sliding window v2:
// thread = 2 channels x 16 consecutive t. BN folded to s*a + c.
// ---------------------------------------------------------------------------
__global__ __launch_bounds__(256) void dwconv_kernel(const bf16* __restrict__ c1,
                                                     const float* __restrict__ dwk,
                                                     const float* __restrict__ dwb,
                                                     const float* __restrict__ bn_g,
                                                     const float* __restrict__ bn_b,
                                                     const float* __restrict__ bn_m,
                                                     const float* __restrict__ bn_v,
                                                     bf16* __restrict__ out) {
    const int C2 = 2 * DD;   // 1024
    const int lin = blockIdx.x * 256 + threadIdx.x;   // 512 chp * 512 chunks
    const int chp = lin & 511;
    const int ch  = chp << 1;
    const int tch = lin >> 9;          // wave-uniform
    const int row0 = tch << 4;         // global row (b*1024 + t), 16 rows
    const int t0   = row0 & (TT - 1);

    float w0[KW], w1[KW];
    #pragma unroll
    for (int i = 0; i < KW; ++i) {
        w0[i] = dwk[i * C2 + ch];
        w1[i] = dwk[i * C2 + ch + 1];
    }
    const float a0 = rsqrtf(bn_v[ch] + 1e-3f) * bn_g[ch];
    const float a1 = rsqrtf(bn_v[ch + 1] + 1e-3f) * bn_g[ch + 1];
    const float c0 = (dwb[ch] - bn_m[ch]) * a0 + bn_b[ch];
    const float c1v = (dwb[ch + 1] - bn_m[ch + 1]) * a1 + bn_b[ch + 1];

    float x0[30], x1[30];
    if (t0 >= KW - 1) {
        #pragma unroll
        for (int i = 0; i < 30; ++i) {
            unsigned u = *(const unsigned*)(c1 + (size_t)(row0 - (KW - 1) + i) * C2 + ch);
            x0[i] = bf2f(u & 0xffff);
            x1[i] = bf2f(u >> 16);
        }
    } else {   // t0 == 0: guard the causal left edge (zero pad)
        #pragma unroll
        for (int i = 0; i < 30; ++i) {
            unsigned u = 0;
            if (t0 - (KW - 1) + i >= 0)
                u = *(const unsigned*)(c1 + (size_t)(row0 - (KW - 1) + i) * C2 + ch);
            x0[i] = bf2f(u & 0xffff);
            x1[i] = bf2f(u >> 16);
        }
    }

    #pragma unroll
    for (int j = 0; j < 16; ++j) {
        float s0 = 0.f, s1 = 0.f;
        #pragma unroll
        for (int i = 0; i < KW; ++i) {
            s0 += x0[j + i] * w0[i];
            s1 += x1[j + i] * w1[i];
        }
        s0 = s0 * a0 + c0;
        s1 = s1 * a1 + c1v;
        s0 = s0 / (1.f + __expf(-s0));
        s1 = s1 / (1.f + __expf(-s1));
        alignas(4) bf16 ob[2] = {__float2bfloat16(s0), __float2bfloat16(s1)};
        *(unsigned*)(out + (size_t)(row0 + j) * C2 + ch) = *(const unsigned*)ob;
    }
}

// ---------------------------------------------------------------------------
extern "C" void kernel_launch(void* const* d_in, const int* in_sizes, int n_in,
                              void* d_out, int out_size, void* d_ws, size_t ws_size,
                              hipStream_t stream) {
    const float* x    = (const float*)d_in[0];
    const float* g1   = (const float*)d_in[1];
    const float* b1   = (const float*)d_in[2];
    const float* Wff1 = (const float*)d_in[3];
    const float* bff1 = (const float*)d_in[4];
    const float* Wff2 = (const float*)d_in[5];
    const float* bff2 = (const float*)d_in[6];
    const float* ga   = (const float*)d_in[7];
    const float* ba   = (const float*)d_in[8];
    const float* Wq   = (const float*)d_in[9];
    const float* bq   = (const float*)d_in[10];
    const float* Wk   = (const float*)d_in[11];
    const float* bk   = (const float*)d_in[12];
    const float* Wv   = (const float*)d_in[13];
    const float* bv   = (const float*)d_in[14];
    const float* Wo   = (const float*)d_in[15];
    const float* bo   = (const float*)d_in[16];
    const float* gc   = (const float*)d_in[17];
    const float* bc   = (const float*)d_in[18];
    const float* Wcp  = (const float*)d_in[19];
    const float* bcp  = (const float*)d_in[20];
    const float* dwk  = (const float*)d_in[21];
    const float* dwb  = (const float*)d_in[22];
    const float* bn_g = (const float*)d_in[23];
    const float* bn_b = (const float*)d_in[24];
    const float* bn_m = (const float*)d_in[25];
    const float* bn_v = (const float*)d_in[26];
    const float* Wco  = (const float*)d_in[27];
    const float* bco  = (const float*)d_in[28];
    const float* g2   = (const float*)d_in[29];
    const float* b2   = (const float*)d_in[30];
    const float* Wf1  = (const float*)d_in[31];
    const float* bf1  = (const float*)d_in[32];
    const float* Wf2  = (const float*)d_in[33];
    const float* bf2  = (const float*)d_in[34];

    float* out = (float*)d_out;

    // ---- workspace layout ----
    char* p = (char*)d_ws;
    bf16* lnb   = (bf16*)p;  p += (size_t)MR * DD * 2;
    bf16* lnab  = (bf16*)p;  p += (size_t)MR * DD * 2;
    bf16* qkvb  = (bf16*)p;  p += (size_t)MR * QKVN * 2;
    bf16* Vtb   = (bf16*)p;  p += (size_t)MR * DD * 2;
    bf16* ctxb  = (bf16*)p;  p += (size_t)MR * DD * 2;
    bf16* xffb  = (bf16*)p;  p += (size_t)MR * DD * 2;
    bf16* bigb  = (bf16*)p;  p += (size_t)MR * FFD * 2;
    bf16* c2b   = (bf16*)p;  p += (size_t)MR * 1024 * 2;
    bf16* Wff1t = (bf16*)p;  p += (size_t)FFD * DD * 2;
    bf16* Wff2t = (bf16*)p;  p += (size_t)DD * FFD * 2;
    bf16* Wqkvt = (bf16*)p;  p += (size_t)QKVN * DD * 2;
    bf16* Wot   = (bf16*)p;  p += (size_t)DD * DD * 2;
    bf16* Wcpt  = (bf16*)p;  p += (size_t)1024 * DD * 2;
    bf16* Wcot  = (bf16*)p;  p += (size_t)DD * 1024 * 2;
    bf16* Wf1t  = (bf16*)p;  p += (size_t)FFD * DD * 2;
    bf16* Wf2t  = (bf16*)p;  p += (size_t)DD * FFD * 2;
    float* bqkv = (float*)p; p += QKVN * 4;

    dim3 blk(256);

    PrepPack P;
    auto set = [&](int i, const float* s, bf16* d, int K, int N, float sc, int off) {
        P.src[i] = s; P.dst[i] = d; P.K[i] = K; P.scale[i] = sc; P.off[i] = off;
        int nt = N / 64, lg = 0; while ((1 << lg) < nt) ++lg; P.lgNT[i] = lg;
    };
    set(0, Wff1, Wff1t, DD,  FFD, 1.f,    0);
    set(1, Wff2, Wff2t, FFD, DD,  1.f,    256);
    set(2, Wq,   Wqkvt,                DD, DD, 0.125f, 512);
    set(3, Wk,   Wqkvt + (size_t)512 * DD,  DD, DD, 1.f, 576);
    set(4, Wv,   Wqkvt + (size_t)1024 * DD, DD, DD, 1.f, 640);
    set(5, Wo,   Wot,   DD,  DD,  1.f,    704);
    set(6, Wcp,  Wcpt,  DD,  1024, 1.f,   768);
    set(7, Wco,  Wcot,  1024, DD, 1.f,    896);
    set(8, Wf1,  Wf1t,  DD,  FFD, 1.f,    1024);
    set(9, Wf2,  Wf2t,  FFD, DD,  1.f,    1280);
    P.bq = bq; P.bk = bk; P.bv = bv; P.bdst = bqkv;
    P.x = x; P.g1 = g1; P.b1 = b1; P.ga = ga; P.ba = ba;
    P.o1 = lnb; P.o2 = lnab;

    // 1. prep: weight transposes + bias concat + dual LN (all independent)
    prep_kernel<<<dim3(1537 + MR / 4), blk, 0, stream>>>(P);
    // 2. fused FF1 + QKV, 256x256 single-barrier tiles (FF1: 256, QKV: 192)
    gemm256_kernel<<<dim3(448), dim3(512), 0, stream>>>(
        lnb, Wff1t, bff1, bigb, lnab, Wqkvt, bqkv, qkvb, Vtb, 256);
    // 3. fused flash-attention + FF2 (parity-interleaved, FF2 2-phase)
    ff2attn_kernel<<<dim3(1024), blk, 0, stream>>>(
        qkvb, Vtb, ctxb, bigb, Wff2t, bff2, xffb);
    // 4+5. x1 = x + 0.5*xff + (ctx @ Wo + bo) -> fp32 out; lnc = LN(x1) -> lnb
    fusedln_kernel<8, 2><<<dim3(256), dim3(512), 0, stream>>>(
        ctxb, Wot, bo, x, xffb, 0.5f, out, gc, bc, lnb);
    // 6. c1 = gelu(lnc @ Wcp + bcp) -> bf16   (nxb = 8)
    bgemm_kernel<128, 2, 0, 1><<<dim3(8 * 64), blk, 0, stream>>>(
        lnb, Wcpt, bcp, nullptr, nullptr, 0.f, 1.f, bigb, 1024, DD, 8);
    // 7. c2 = swish(BN(dwconv(c1))) -> bf16   (16 t per thread)
    dwconv_kernel<<<dim3(MR * 512 / 16 / 256), blk, 0, stream>>>(
        bigb, dwk, dwb, bn_g, bn_b, bn_m, bn_v, c2b);
    // 8+9. x2 = x1 + (c2 @ Wco + bco) -> fp32 out (in-place); ln2 -> lnb
    fusedln_kernel<16, 1><<<dim3(256), dim3(512), 0, stream>>>(
        c2b, Wcot, bco, out, nullptr, 0.f, out, g2, b2, lnb);
    // 10. h2 = relu(ln2 @ Wf1 + bf1) -> bf16, single-barrier 256^2 kernel
    gemm256_kernel<<<dim3(256), dim3(512), 0, stream>>>(
        lnb, Wf1t, bf1, bigb, nullptr, nullptr, nullptr, nullptr, nullptr, 256);
    // 11. out = x2 + (h2 @ Wf2 + bf2) -> fp32 d_out   (BN=64, nxb=8)
    bgemm_kernel<64, 0, 1, 0><<<dim3(8 * 64), blk, 0, stream>>>(
        bigb, Wf2t, bf2, out, nullptr, 0.f, 1.f, out, DD, FFD, 8);
}